// Round 2
// baseline (4818.416 us; speedup 1.0000x reference)
//
#include <hip/hip_runtime.h>
#include <hip/hip_bf16.h>

#define NN 20000
#define EU 320000
#define ED 640000
#define FIN 128
#define HD  128
#define NC  8
#define BP_ITERS 100

#define LOG2E 1.4426950408889634f
#define LN2   0.6931471805599453f

// ---- workspace layout (4-byte units) ----
enum {
  OFF_FLAG   = 0,                      // 4 ints
  OFF_DINV   = 4,                      // NN floats
  OFF_COUNT  = OFF_DINV  + NN,         // NN ints
  OFF_ROWPTR = OFF_COUNT + NN,         // NN+4 ints
  OFF_FILL   = OFF_ROWPTR+ NN + 4,     // NN ints
  OFF_EID    = OFF_FILL  + NN,         // ED ints
  OFF_SRC    = OFF_EID   + ED,         // ED ints
  OFF_HW1    = OFF_SRC   + ED,         // NN*HD floats
  OFF_H1     = OFF_HW1   + NN*HD,      // NN*HD floats
  OFF_HW2    = OFF_H1    + NN*HD,      // NN*NC floats
  OFF_PHIU   = OFF_HW2   + NN*NC,      // NN*NC floats
  OFF_PHIB   = OFF_PHIU  + NN*NC,      // 64 floats
  OFF_NPHI   = OFF_PHIB  + 64,         // NN*NC floats
  OFF_MA     = OFF_NPHI  + NN*NC,      // ED*NC floats
  OFF_MB     = OFF_MA    + ED*NC,      // ED*NC floats
  WS_WORDS   = OFF_MB    + ED*NC
};

__device__ __forceinline__ float fexp2(float x) {
#if __has_builtin(__builtin_amdgcn_exp2f)
  return __builtin_amdgcn_exp2f(x);
#else
  return exp2f(x);
#endif
}
__device__ __forceinline__ float flog2(float x) {
#if __has_builtin(__builtin_amdgcn_logf)
  return __builtin_amdgcn_logf(x);
#else
  return log2f(x);
#endif
}

// detect whether train_mask is byte(bool) or int32 layout.
// first 5000 words are valid under both; packed bools give words >1 w.h.p.
__global__ void k_detect(const unsigned* tm, int* flag) {
  __shared__ int bad;
  if (threadIdx.x == 0) bad = 0;
  __syncthreads();
  for (int i = threadIdx.x; i < NN / 4; i += blockDim.x) {
    if (tm[i] > 1u) atomicOr(&bad, 1);
  }
  __syncthreads();
  if (threadIdx.x == 0) flag[0] = bad;  // 1 => byte layout
}

__global__ void k_count(const int* ei, int* cnt) {
  int e = blockIdx.x * blockDim.x + threadIdx.x;
  if (e < ED) {
    int dst = ei[e < EU ? e + EU : e - EU];
    atomicAdd(&cnt[dst], 1);
  }
}

__global__ void k_scan(const int* cnt, int* rowptr) {
  __shared__ int s[1024];
  const int T = 1024, CH = (NN + T - 1) / T;  // 20
  int t = threadIdx.x;
  int base = t * CH;
  int loc = 0;
  for (int k = 0; k < CH; k++) {
    int idx = base + k;
    if (idx < NN) loc += cnt[idx];
  }
  s[t] = loc;
  __syncthreads();
  for (int off = 1; off < T; off <<= 1) {
    int v = (t >= off) ? s[t - off] : 0;
    __syncthreads();
    s[t] += v;
    __syncthreads();
  }
  int run = s[t] - loc;  // exclusive
  for (int k = 0; k < CH; k++) {
    int idx = base + k;
    if (idx < NN) { rowptr[idx] = run; run += cnt[idx]; }
  }
  if (t == T - 1) rowptr[NN] = run;
}

__global__ void k_dinv(const int* cnt, float* dinv) {
  int v = blockIdx.x * blockDim.x + threadIdx.x;
  if (v < NN) dinv[v] = rsqrtf((float)(cnt[v] + 1));
}

__global__ void k_fill(const int* ei, const int* rowptr, int* fill, int* eid, int* srcarr) {
  int e = blockIdx.x * blockDim.x + threadIdx.x;
  if (e < ED) {
    int dst = ei[e < EU ? e + EU : e - EU];
    int src = ei[e];
    int p = rowptr[dst] + atomicAdd(&fill[dst], 1);
    eid[p] = e;
    srcarr[p] = src;
  }
}

// hw1 = (x @ W1) * dinv[row]   (pre-scaled for aggregation)
__global__ __launch_bounds__(256) void k_gemm1(const float* __restrict__ x,
                                               const float* __restrict__ W1,
                                               const float* __restrict__ dinv,
                                               float* __restrict__ hw1) {
  __shared__ float Ws[FIN * HD];  // 64KB
  int t = threadIdx.x;
  for (int i = t * 4; i < FIN * HD; i += 256 * 4)
    *(float4*)&Ws[i] = *(const float4*)&W1[i];
  __syncthreads();
  int c = t & 127, half = t >> 7;
  int r0 = blockIdx.x * 8 + half * 4;
  float acc[4] = {0.f, 0.f, 0.f, 0.f};
  for (int k = 0; k < FIN; k++) {
    float w = Ws[k * HD + c];
#pragma unroll
    for (int r = 0; r < 4; r++)
      acc[r] += x[(r0 + r) * FIN + k] * w;
  }
#pragma unroll
  for (int r = 0; r < 4; r++)
    hw1[(r0 + r) * HD + c] = acc[r] * dinv[r0 + r];
}

// h1[v] = relu(dinv[v]*(sum_in hw1[u] + hw1[v]) + b1)
__global__ __launch_bounds__(128) void k_agg1(const float* __restrict__ hw1,
                                              const float* __restrict__ dinv,
                                              const int* __restrict__ rowptr,
                                              const int* __restrict__ srcarr,
                                              const float* __restrict__ b1,
                                              float* __restrict__ h1) {
  int v = blockIdx.x;
  int f = threadIdx.x;
  int s0 = rowptr[v], s1 = rowptr[v + 1];
  float acc = 0.f;
  for (int s = s0; s < s1; s++) {
    int u = srcarr[s];
    acc += hw1[u * HD + f];
  }
  float dv = dinv[v];
  float val = dv * (acc + hw1[v * HD + f]) + b1[f];
  h1[v * HD + f] = fmaxf(val, 0.f);
}

// hw2 = (h1 @ W2) * dinv[row]
__global__ __launch_bounds__(256) void k_gemm2(const float* __restrict__ h1,
                                               const float* __restrict__ W2,
                                               const float* __restrict__ dinv,
                                               float* __restrict__ hw2) {
  __shared__ float Ws[HD * NC];  // 4KB
  int t = threadIdx.x;
  for (int i = t; i < HD * NC; i += 256) Ws[i] = W2[i];
  __syncthreads();
  int v = blockIdx.x * 256 + t;
  if (v >= NN) return;
  float acc[NC];
#pragma unroll
  for (int c = 0; c < NC; c++) acc[c] = 0.f;
  const float4* hp = (const float4*)&h1[v * HD];
  for (int k4 = 0; k4 < HD / 4; k4++) {
    float4 h4 = hp[k4];
    float hv[4] = {h4.x, h4.y, h4.z, h4.w};
#pragma unroll
    for (int j = 0; j < 4; j++) {
      int k = k4 * 4 + j;
#pragma unroll
      for (int c = 0; c < NC; c++) acc[c] += hv[j] * Ws[k * NC + c];
    }
  }
  float dv = dinv[v];
#pragma unroll
  for (int c = 0; c < NC; c++) hw2[v * NC + c] = acc[c] * dv;
}

// unary -> phi_u  (clamping logic of the reference), 32 nodes x 8 lanes per block
__global__ __launch_bounds__(256) void k_agg2pre(const float* __restrict__ hw2,
                                                 const float* __restrict__ dinv,
                                                 const int* __restrict__ rowptr,
                                                 const int* __restrict__ srcarr,
                                                 const float* __restrict__ b2,
                                                 const int* __restrict__ target,
                                                 const void* __restrict__ tmask,
                                                 const int* __restrict__ flag,
                                                 float* __restrict__ phi_u) {
  int t = threadIdx.x;
  int node = blockIdx.x * 32 + (t >> 3);
  int c = t & 7;
  if (node >= NN) return;
  int s0 = rowptr[node], s1 = rowptr[node + 1];
  float acc = 0.f;
  for (int s = s0; s < s1; s++) {
    int u = srcarr[s];
    acc += hw2[u * NC + c];
  }
  float dv = dinv[node];
  float unary = dv * (acc + hw2[node * NC + c]) + b2[c];
  float e = -unary;
  int tgt = target[node];
  float gt = __shfl(e, tgt, 8);  // gather BEFORE masking
  bool mk;
  if (flag[0]) mk = ((const unsigned char*)tmask)[node] != 0;
  else         mk = ((const int*)tmask)[node] != 0;
  if (mk) e = (c == tgt) ? gt : 1e5f;
  float mn = e;
  mn = fminf(mn, __shfl_xor(mn, 1, 8));
  mn = fminf(mn, __shfl_xor(mn, 2, 8));
  mn = fminf(mn, __shfl_xor(mn, 4, 8));
  e = fminf(e - mn, 20.0f);
  phi_u[node * NC + c] = -e;
}

// phi_b = B - max(B), B = (binary + binary^T)/2
__global__ void k_phib(const float* __restrict__ binary, float* __restrict__ phib) {
  int t = threadIdx.x;  // 64
  int i = t >> 3, j = t & 7;
  float B = 0.5f * (binary[i * NC + j] + binary[j * NC + i]);
  float mx = B;
#pragma unroll
  for (int d = 1; d < 64; d <<= 1) mx = fmaxf(mx, __shfl_xor(mx, d, 64));
  phib[t] = B - mx;
}

// nphi[v] = phi_u[v] + sum of incoming messages
__global__ __launch_bounds__(256) void k_node(const float* __restrict__ m,
                                              const float* __restrict__ phi_u,
                                              const int* __restrict__ rowptr,
                                              const int* __restrict__ eid,
                                              float* __restrict__ nphi) {
  int t = threadIdx.x;
  int node = blockIdx.x * 32 + (t >> 3);
  int c = t & 7;
  if (node >= NN) return;
  int s0 = rowptr[node], s1 = rowptr[node + 1];
  float acc = 0.f;
  for (int s = s0; s < s1; s++) {
    int e = eid[s];
    acc += m[e * NC + c];
  }
  nphi[node * NC + c] = phi_u[node * NC + c] + acc;
}

// per-edge BP update
__global__ __launch_bounds__(256) void k_edge(const float* __restrict__ m,
                                              const float* __restrict__ nphi,
                                              const float* __restrict__ phib_g,
                                              const float* __restrict__ rezero,
                                              const int* __restrict__ ei,
                                              float* __restrict__ mout) {
  __shared__ float pb[64];
  int t = threadIdx.x;
  if (t < 64) pb[t] = phib_g[t];
  __syncthreads();
  int e = blockIdx.x * 256 + t;
  if (e >= ED) return;
  int src = ei[e];
  int er = (e < EU) ? e + EU : e - EU;
  float s = rezero[(e < EU) ? e : e - EU];

  float4 n0 = *(const float4*)&nphi[src * NC];
  float4 n1 = *(const float4*)&nphi[src * NC + 4];
  float4 m0 = *(const float4*)&m[er * NC];
  float4 m1 = *(const float4*)&m[er * NC + 4];
  float hm[8] = {n0.x - m0.x, n0.y - m0.y, n0.z - m0.z, n0.w - m0.w,
                 n1.x - m1.x, n1.y - m1.y, n1.z - m1.z, n1.w - m1.w};
  float mx = hm[0];
#pragma unroll
  for (int i = 1; i < 8; i++) mx = fmaxf(mx, hm[i]);
  float a[8];
#pragma unroll
  for (int i = 0; i < 8; i++) a[i] = (hm[i] - mx) * LOG2E;
  float sl = s * LOG2E;
  float out[8];
#pragma unroll
  for (int j = 0; j < 8; j++) {
    float S = 0.f;
#pragma unroll
    for (int i = 0; i < 8; i++)
      S += fexp2(fmaf(sl, pb[i * 8 + j], a[i]));
    out[j] = fmaf(flog2(S), LN2, mx);
  }
  // renormalize (exact LSE over labels, matches reference)
  float mm = out[0];
#pragma unroll
  for (int j = 1; j < 8; j++) mm = fmaxf(mm, out[j]);
  float Z = 0.f;
#pragma unroll
  for (int j = 0; j < 8; j++) Z += fexp2((out[j] - mm) * LOG2E);
  float lse = fmaf(flog2(Z), LN2, mm);
  float4 o0 = make_float4(out[0] - lse, out[1] - lse, out[2] - lse, out[3] - lse);
  float4 o1 = make_float4(out[4] - lse, out[5] - lse, out[6] - lse, out[7] - lse);
  *(float4*)&mout[e * NC] = o0;
  *(float4*)&mout[e * NC + 4] = o1;
}

// beliefs -> log_softmax -> d_out
__global__ __launch_bounds__(256) void k_final(const float* __restrict__ m,
                                               const float* __restrict__ phi_u,
                                               const int* __restrict__ rowptr,
                                               const int* __restrict__ eid,
                                               float* __restrict__ out) {
  int t = threadIdx.x;
  int node = blockIdx.x * 32 + (t >> 3);
  int c = t & 7;
  if (node >= NN) return;
  int s0 = rowptr[node], s1 = rowptr[node + 1];
  float acc = phi_u[node * NC + c];
  for (int s = s0; s < s1; s++) {
    int e = eid[s];
    acc += m[e * NC + c];
  }
  float mx = acc;
  mx = fmaxf(mx, __shfl_xor(mx, 1, 8));
  mx = fmaxf(mx, __shfl_xor(mx, 2, 8));
  mx = fmaxf(mx, __shfl_xor(mx, 4, 8));
  float ex = fexp2((acc - mx) * LOG2E);
  float Z = ex;
  Z += __shfl_xor(Z, 1, 8);
  Z += __shfl_xor(Z, 2, 8);
  Z += __shfl_xor(Z, 4, 8);
  out[node * NC + c] = acc - fmaf(flog2(Z), LN2, mx);
}

extern "C" void kernel_launch(void* const* d_in, const int* in_sizes, int n_in,
                              void* d_out, int out_size, void* d_ws, size_t ws_size,
                              hipStream_t stream) {
  const float* x      = (const float*)d_in[0];
  const int*   ei     = (const int*)d_in[1];
  const void*  tmask  = d_in[2];
  const int*   target = (const int*)d_in[3];
  const float* W1     = (const float*)d_in[4];
  const float* b1     = (const float*)d_in[5];
  const float* W2     = (const float*)d_in[6];
  const float* b2     = (const float*)d_in[7];
  const float* binary = (const float*)d_in[8];
  const float* rezero = (const float*)d_in[9];

  float* ws  = (float*)d_ws;
  int*   wsi = (int*)d_ws;

  int*   flag   = wsi + OFF_FLAG;
  float* dinv   = ws  + OFF_DINV;
  int*   cnt    = wsi + OFF_COUNT;
  int*   rowptr = wsi + OFF_ROWPTR;
  int*   fill   = wsi + OFF_FILL;
  int*   eid    = wsi + OFF_EID;
  int*   srcarr = wsi + OFF_SRC;
  float* hw1    = ws + OFF_HW1;
  float* h1     = ws + OFF_H1;
  float* hw2    = ws + OFF_HW2;
  float* phiu   = ws + OFF_PHIU;
  float* phib   = ws + OFF_PHIB;
  float* nphi   = ws + OFF_NPHI;
  float* mA     = ws + OFF_MA;
  float* mB     = ws + OFF_MB;

  hipMemsetAsync(cnt, 0, NN * sizeof(int), stream);
  hipMemsetAsync(fill, 0, NN * sizeof(int), stream);
  hipMemsetAsync(mA, 0, (size_t)ED * NC * sizeof(float), stream);

  k_detect<<<1, 1024, 0, stream>>>((const unsigned*)tmask, flag);
  k_count<<<(ED + 255) / 256, 256, 0, stream>>>(ei, cnt);
  k_scan<<<1, 1024, 0, stream>>>(cnt, rowptr);
  k_dinv<<<(NN + 255) / 256, 256, 0, stream>>>(cnt, dinv);
  k_fill<<<(ED + 255) / 256, 256, 0, stream>>>(ei, rowptr, fill, eid, srcarr);

  k_gemm1<<<NN / 8, 256, 0, stream>>>(x, W1, dinv, hw1);
  k_agg1<<<NN, 128, 0, stream>>>(hw1, dinv, rowptr, srcarr, b1, h1);
  k_gemm2<<<(NN + 255) / 256, 256, 0, stream>>>(h1, W2, dinv, hw2);
  k_agg2pre<<<NN / 32, 256, 0, stream>>>(hw2, dinv, rowptr, srcarr, b2, target,
                                         tmask, flag, phiu);
  k_phib<<<1, 64, 0, stream>>>(binary, phib);

  float* mcur = mA;
  float* mnxt = mB;
  for (int it = 0; it < BP_ITERS; it++) {
    k_node<<<NN / 32, 256, 0, stream>>>(mcur, phiu, rowptr, eid, nphi);
    k_edge<<<ED / 256, 256, 0, stream>>>(mcur, nphi, phib, rezero, ei, mnxt);
    float* tmp = mcur; mcur = mnxt; mnxt = tmp;
  }

  k_final<<<NN / 32, 256, 0, stream>>>(mcur, phiu, rowptr, eid, (float*)d_out);
}

// Round 5
// 3349.866 us; speedup vs baseline: 1.4384x; 1.4384x over previous
//
#include <hip/hip_runtime.h>
#include <hip/hip_bf16.h>

#define NN 20000
#define EU 320000
#define ED 640000
#define FIN 128
#define HD  128
#define NC  8
#define BP_ITERS 100
#define NPB 4      // nodes (waves) per block in BP kernels
#define GMAX 16    // register-cached edge groups (GMAX*8 = 128 edges max fast path)

#define LOG2E 1.4426950408889634f
#define LN2   0.6931471805599453f

// ---- workspace layout (4-byte units); hw1 aliases mA, h1 aliases mB ----
enum {
  OFF_FLAG   = 0,                      // 4 ints
  OFF_DINV   = 4,                      // NN floats
  OFF_COUNT  = OFF_DINV  + NN,         // NN ints
  OFF_ROWPTR = OFF_COUNT + NN,         // NN+4 ints
  OFF_FILL   = OFF_ROWPTR+ NN + 4,     // NN ints
  OFF_EID    = OFF_FILL  + NN,         // ED ints  (slot -> directed edge id)
  OFF_POS    = OFF_EID   + ED,         // ED ints  (edge id -> slot)
  OFF_DST    = OFF_POS   + ED,         // ED ints  (slot -> dst node)
  OFF_REV    = OFF_DST   + ED,         // ED ints  (slot -> slot of reverse edge)
  OFF_SCALE  = OFF_REV   + ED,         // ED floats (slot -> rezero scale)
  OFF_HW2    = OFF_SCALE + ED,         // NN*NC floats
  OFF_PHIU   = OFF_HW2   + NN*NC,      // NN*NC floats
  OFF_PHIB   = OFF_PHIU  + NN*NC,      // 64 floats
  OFF_MA     = OFF_PHIB  + 64,         // ED*NC floats (also hw1: NN*HD <= ED*NC)
  OFF_MB     = OFF_MA    + ED*NC,      // ED*NC floats (also h1)
  WS_WORDS   = OFF_MB    + ED*NC
};

__device__ __forceinline__ float fexp2(float x) {
#if __has_builtin(__builtin_amdgcn_exp2f)
  return __builtin_amdgcn_exp2f(x);
#else
  return exp2f(x);
#endif
}
__device__ __forceinline__ float flog2(float x) {
#if __has_builtin(__builtin_amdgcn_logf)
  return __builtin_amdgcn_logf(x);
#else
  return log2f(x);
#endif
}

// detect whether train_mask is byte(bool) or int32 layout.
__global__ void k_detect(const unsigned* tm, int* flag) {
  __shared__ int bad;
  if (threadIdx.x == 0) bad = 0;
  __syncthreads();
  for (int i = threadIdx.x; i < NN / 4; i += blockDim.x) {
    if (tm[i] > 1u) atomicOr(&bad, 1);
  }
  __syncthreads();
  if (threadIdx.x == 0) flag[0] = bad;  // 1 => byte layout
}

// count by SRC (symmetric edge list => same as by dst)
__global__ void k_count(const int* ei, int* cnt) {
  int e = blockIdx.x * blockDim.x + threadIdx.x;
  if (e < ED) atomicAdd(&cnt[ei[e]], 1);
}

__global__ void k_scan(const int* cnt, int* rowptr) {
  __shared__ int s[1024];
  const int T = 1024, CH = (NN + T - 1) / T;
  int t = threadIdx.x;
  int base = t * CH;
  int loc = 0;
  for (int k = 0; k < CH; k++) {
    int idx = base + k;
    if (idx < NN) loc += cnt[idx];
  }
  s[t] = loc;
  __syncthreads();
  for (int off = 1; off < T; off <<= 1) {
    int v = (t >= off) ? s[t - off] : 0;
    __syncthreads();
    s[t] += v;
    __syncthreads();
  }
  int run = s[t] - loc;  // exclusive
  for (int k = 0; k < CH; k++) {
    int idx = base + k;
    if (idx < NN) { rowptr[idx] = run; run += cnt[idx]; }
  }
  if (t == T - 1) rowptr[NN] = run;
}

__global__ void k_dinv(const int* cnt, float* dinv) {
  int v = blockIdx.x * blockDim.x + threadIdx.x;
  if (v < NN) dinv[v] = rsqrtf((float)(cnt[v] + 1));
}

// fill src-CSR: slot -> edge, edge -> slot, slot -> dst node, slot -> scale
__global__ void k_fill(const int* ei, const int* rowptr, int* fill,
                       int* eid, int* pos, int* dstarr, float* scale_s,
                       const float* rezero) {
  int e = blockIdx.x * blockDim.x + threadIdx.x;
  if (e < ED) {
    int src = ei[e];
    int er = (e < EU) ? e + EU : e - EU;
    int p = rowptr[src] + atomicAdd(&fill[src], 1);
    eid[p] = e;
    pos[e] = p;
    dstarr[p] = ei[er];                     // dst node of this edge
    scale_s[p] = rezero[(e < EU) ? e : e - EU];
  }
}

__global__ void k_rev(const int* eid, const int* pos, int* revslot) {
  int p = blockIdx.x * blockDim.x + threadIdx.x;
  if (p < ED) {
    int e = eid[p];
    int er = (e < EU) ? e + EU : e - EU;
    revslot[p] = pos[er];
  }
}

// hw1 = (x @ W1) * dinv[row]
__global__ __launch_bounds__(256) void k_gemm1(const float* __restrict__ x,
                                               const float* __restrict__ W1,
                                               const float* __restrict__ dinv,
                                               float* __restrict__ hw1) {
  __shared__ float Ws[FIN * HD];  // 64KB
  int t = threadIdx.x;
  for (int i = t * 4; i < FIN * HD; i += 256 * 4)
    *(float4*)&Ws[i] = *(const float4*)&W1[i];
  __syncthreads();
  int c = t & 127, half = t >> 7;
  int r0 = blockIdx.x * 8 + half * 4;
  float acc[4] = {0.f, 0.f, 0.f, 0.f};
  for (int k = 0; k < FIN; k++) {
    float w = Ws[k * HD + c];
#pragma unroll
    for (int r = 0; r < 4; r++)
      acc[r] += x[(r0 + r) * FIN + k] * w;
  }
#pragma unroll
  for (int r = 0; r < 4; r++)
    hw1[(r0 + r) * HD + c] = acc[r] * dinv[r0 + r];
}

// h1[v] = relu(dinv[v]*(sum_neighbors hw1[u] + hw1[v]) + b1)
// neighbors of v = dstarr over v's out-row (symmetric edge list)
__global__ __launch_bounds__(128) void k_agg1(const float* __restrict__ hw1,
                                              const float* __restrict__ dinv,
                                              const int* __restrict__ rowptr,
                                              const int* __restrict__ dstarr,
                                              const float* __restrict__ b1,
                                              float* __restrict__ h1) {
  int v = blockIdx.x;
  int f = threadIdx.x;
  int s0 = rowptr[v], s1 = rowptr[v + 1];
  float a0 = 0.f, a1 = 0.f, a2 = 0.f, a3 = 0.f;
  int s = s0;
  for (; s + 4 <= s1; s += 4) {
    int u0 = dstarr[s], u1 = dstarr[s + 1], u2 = dstarr[s + 2], u3 = dstarr[s + 3];
    a0 += hw1[u0 * HD + f];
    a1 += hw1[u1 * HD + f];
    a2 += hw1[u2 * HD + f];
    a3 += hw1[u3 * HD + f];
  }
  for (; s < s1; s++) a0 += hw1[dstarr[s] * HD + f];
  float acc = (a0 + a1) + (a2 + a3);
  float dv = dinv[v];
  float val = dv * (acc + hw1[v * HD + f]) + b1[f];
  h1[v * HD + f] = fmaxf(val, 0.f);
}

// hw2 = (h1 @ W2) * dinv[row]
__global__ __launch_bounds__(256) void k_gemm2(const float* __restrict__ h1,
                                               const float* __restrict__ W2,
                                               const float* __restrict__ dinv,
                                               float* __restrict__ hw2) {
  __shared__ float Ws[HD * NC];
  int t = threadIdx.x;
  for (int i = t; i < HD * NC; i += 256) Ws[i] = W2[i];
  __syncthreads();
  int v = blockIdx.x * 256 + t;
  if (v >= NN) return;
  float acc[NC];
#pragma unroll
  for (int c = 0; c < NC; c++) acc[c] = 0.f;
  const float4* hp = (const float4*)&h1[v * HD];
  for (int k4 = 0; k4 < HD / 4; k4++) {
    float4 h4 = hp[k4];
    float hv[4] = {h4.x, h4.y, h4.z, h4.w};
#pragma unroll
    for (int j = 0; j < 4; j++) {
      int k = k4 * 4 + j;
#pragma unroll
      for (int c = 0; c < NC; c++) acc[c] += hv[j] * Ws[k * NC + c];
    }
  }
  float dv = dinv[v];
#pragma unroll
  for (int c = 0; c < NC; c++) hw2[v * NC + c] = acc[c] * dv;
}

// unary -> phi_u (reference clamping), 32 nodes x 8 lanes per block
__global__ __launch_bounds__(256) void k_agg2pre(const float* __restrict__ hw2,
                                                 const float* __restrict__ dinv,
                                                 const int* __restrict__ rowptr,
                                                 const int* __restrict__ dstarr,
                                                 const float* __restrict__ b2,
                                                 const int* __restrict__ target,
                                                 const void* __restrict__ tmask,
                                                 const int* __restrict__ flag,
                                                 float* __restrict__ phi_u) {
  int t = threadIdx.x;
  int node = blockIdx.x * 32 + (t >> 3);
  int c = t & 7;
  if (node >= NN) return;
  int s0 = rowptr[node], s1 = rowptr[node + 1];
  float acc = 0.f;
  for (int s = s0; s < s1; s++) {
    int u = dstarr[s];
    acc += hw2[u * NC + c];
  }
  float dv = dinv[node];
  float unary = dv * (acc + hw2[node * NC + c]) + b2[c];
  float e = -unary;
  int tgt = target[node];
  float gt = __shfl(e, (t & ~7) | tgt, 64);  // GT energy gathered before masking
  bool mk;
  if (flag[0]) mk = ((const unsigned char*)tmask)[node] != 0;
  else         mk = ((const int*)tmask)[node] != 0;
  if (mk) e = (c == tgt) ? gt : 1e5f;
  float mn = e;
  mn = fminf(mn, __shfl_xor(mn, 1));
  mn = fminf(mn, __shfl_xor(mn, 2));
  mn = fminf(mn, __shfl_xor(mn, 4));
  e = fminf(e - mn, 20.0f);
  phi_u[node * NC + c] = -e;
}

// phi_b = B - max(B), B = (binary + binary^T)/2
__global__ void k_phib(const float* __restrict__ binary, float* __restrict__ phib) {
  int t = threadIdx.x;  // 64
  int i = t >> 3, j = t & 7;
  float B = 0.5f * (binary[i * NC + j] + binary[j * NC + i]);
  float mx = B;
#pragma unroll
  for (int d = 1; d < 64; d <<= 1) mx = fmaxf(mx, __shfl_xor(mx, d));
  phib[t] = B - mx;
}

// ---- fused BP iteration: one wave per node ----
// messages stored in src-CSR slot order; incoming messages of v are
// m[revslot[q]] for q in v's row; outgoing m_new written to own slots.
__global__ __launch_bounds__(256) void k_bp(const float* __restrict__ m,
                                            float* __restrict__ mout,
                                            const float* __restrict__ phiu,
                                            const int* __restrict__ srowptr,
                                            const int* __restrict__ revslot,
                                            const float* __restrict__ scale_s,
                                            const float* __restrict__ phib_g) {
  __shared__ float pb[64];
  int t = threadIdx.x;
  if (t < 64) pb[t] = phib_g[t];
  __syncthreads();
  int w = t >> 6, l = t & 63, le = l >> 3, c = l & 7;
  int v = blockIdx.x * NPB + w;
  int s0 = srowptr[v], deg = srowptr[v + 1] - s0;
  int ng = (deg + 7) >> 3;
  float pbr[8];
#pragma unroll
  for (int i = 0; i < 8; i++) pbr[i] = pb[i * 8 + c];

  // pass 1: gather incoming messages (cached in registers), accumulate node_in
  float mv[GMAX];
  float ni = 0.f;
#pragma unroll
  for (int g = 0; g < GMAX; g++) {
    mv[g] = 0.f;
    if (g < ng) {
      int q = g * 8 + le;
      if (q < deg) mv[g] = m[revslot[s0 + q] * 8 + c];
      ni += mv[g];
    }
  }
  for (int g = GMAX; g < ng; g++) {  // cold overflow path (deg > 128)
    int q = g * 8 + le;
    if (q < deg) ni += m[revslot[s0 + q] * 8 + c];
  }
  ni += __shfl_xor(ni, 8);
  ni += __shfl_xor(ni, 16);
  ni += __shfl_xor(ni, 32);
  float nph = phiu[v * 8 + c] + ni;   // uniform across le groups

  // pass 2: per outgoing edge q = g*8+le, lane computes output class c
#pragma unroll
  for (int g = 0; g < GMAX; g++) {
    if (g < ng) {
      int q = g * 8 + le;
      float hm = nph - mv[g];
      float mx = hm;
      mx = fmaxf(mx, __shfl_xor(mx, 1));
      mx = fmaxf(mx, __shfl_xor(mx, 2));
      mx = fmaxf(mx, __shfl_xor(mx, 4));
      float a = (hm - mx) * LOG2E;
      float sl = scale_s[s0 + (q < deg ? q : 0)] * LOG2E;
      float S = 0.f;
#pragma unroll
      for (int i = 0; i < 8; i++) {
        float ai = __shfl(a, (l & 56) | i, 64);
        S += fexp2(fmaf(sl, pbr[i], ai));
      }
      float out = fmaf(flog2(S), LN2, mx);
      float mm = out;
      mm = fmaxf(mm, __shfl_xor(mm, 1));
      mm = fmaxf(mm, __shfl_xor(mm, 2));
      mm = fmaxf(mm, __shfl_xor(mm, 4));
      float Z = fexp2((out - mm) * LOG2E);
      Z += __shfl_xor(Z, 1);
      Z += __shfl_xor(Z, 2);
      Z += __shfl_xor(Z, 4);
      float res = out - fmaf(flog2(Z), LN2, mm);
      if (q < deg) mout[(s0 + q) * 8 + c] = res;
    }
  }
  for (int g = GMAX; g < ng; g++) {  // cold overflow path
    int q = g * 8 + le;
    float mvg = (q < deg) ? m[revslot[s0 + q] * 8 + c] : 0.f;
    float hm = nph - mvg;
    float mx = hm;
    mx = fmaxf(mx, __shfl_xor(mx, 1));
    mx = fmaxf(mx, __shfl_xor(mx, 2));
    mx = fmaxf(mx, __shfl_xor(mx, 4));
    float a = (hm - mx) * LOG2E;
    float sl = scale_s[s0 + (q < deg ? q : 0)] * LOG2E;
    float S = 0.f;
#pragma unroll
    for (int i = 0; i < 8; i++) {
      float ai = __shfl(a, (l & 56) | i, 64);
      S += fexp2(fmaf(sl, pbr[i], ai));
    }
    float out = fmaf(flog2(S), LN2, mx);
    float mm = out;
    mm = fmaxf(mm, __shfl_xor(mm, 1));
    mm = fmaxf(mm, __shfl_xor(mm, 2));
    mm = fmaxf(mm, __shfl_xor(mm, 4));
    float Z = fexp2((out - mm) * LOG2E);
    Z += __shfl_xor(Z, 1);
    Z += __shfl_xor(Z, 2);
    Z += __shfl_xor(Z, 4);
    float res = out - fmaf(flog2(Z), LN2, mm);
    if (q < deg) mout[(s0 + q) * 8 + c] = res;
  }
}

// beliefs = phi_u + sum incoming; log_softmax -> out
__global__ __launch_bounds__(256) void k_final(const float* __restrict__ m,
                                               const float* __restrict__ phiu,
                                               const int* __restrict__ srowptr,
                                               const int* __restrict__ revslot,
                                               float* __restrict__ out) {
  int t = threadIdx.x;
  int w = t >> 6, l = t & 63, le = l >> 3, c = l & 7;
  int v = blockIdx.x * NPB + w;
  int s0 = srowptr[v], deg = srowptr[v + 1] - s0;
  float ni = 0.f;
  for (int q = le; q < deg; q += 8) ni += m[revslot[s0 + q] * 8 + c];
  ni += __shfl_xor(ni, 8);
  ni += __shfl_xor(ni, 16);
  ni += __shfl_xor(ni, 32);
  float bel = phiu[v * 8 + c] + ni;
  float mx = bel;
  mx = fmaxf(mx, __shfl_xor(mx, 1));
  mx = fmaxf(mx, __shfl_xor(mx, 2));
  mx = fmaxf(mx, __shfl_xor(mx, 4));
  float Z = fexp2((bel - mx) * LOG2E);
  Z += __shfl_xor(Z, 1);
  Z += __shfl_xor(Z, 2);
  Z += __shfl_xor(Z, 4);
  out[v * 8 + c] = bel - fmaf(flog2(Z), LN2, mx);
}

extern "C" void kernel_launch(void* const* d_in, const int* in_sizes, int n_in,
                              void* d_out, int out_size, void* d_ws, size_t ws_size,
                              hipStream_t stream) {
  const float* x      = (const float*)d_in[0];
  const int*   ei     = (const int*)d_in[1];
  const void*  tmask  = d_in[2];
  const int*   target = (const int*)d_in[3];
  const float* W1     = (const float*)d_in[4];
  const float* b1     = (const float*)d_in[5];
  const float* W2     = (const float*)d_in[6];
  const float* b2     = (const float*)d_in[7];
  const float* binary = (const float*)d_in[8];
  const float* rezero = (const float*)d_in[9];

  float* ws  = (float*)d_ws;
  int*   wsi = (int*)d_ws;

  int*   flag    = wsi + OFF_FLAG;
  float* dinv    = ws  + OFF_DINV;
  int*   cnt     = wsi + OFF_COUNT;
  int*   rowptr  = wsi + OFF_ROWPTR;
  int*   fill    = wsi + OFF_FILL;
  int*   eid     = wsi + OFF_EID;
  int*   pos     = wsi + OFF_POS;
  int*   dstarr  = wsi + OFF_DST;
  int*   revslot = wsi + OFF_REV;
  float* scale_s = ws  + OFF_SCALE;
  float* hw2     = ws  + OFF_HW2;
  float* phiu    = ws  + OFF_PHIU;
  float* phib    = ws  + OFF_PHIB;
  float* mA      = ws  + OFF_MA;
  float* mB      = ws  + OFF_MB;
  float* hw1     = mA;  // aliased: GCN scratch reuses message buffers
  float* h1      = mB;

  hipMemsetAsync(cnt, 0, NN * sizeof(int), stream);
  hipMemsetAsync(fill, 0, NN * sizeof(int), stream);

  k_detect<<<1, 1024, 0, stream>>>((const unsigned*)tmask, flag);
  k_count<<<(ED + 255) / 256, 256, 0, stream>>>(ei, cnt);
  k_scan<<<1, 1024, 0, stream>>>(cnt, rowptr);
  k_dinv<<<(NN + 255) / 256, 256, 0, stream>>>(cnt, dinv);
  k_fill<<<(ED + 255) / 256, 256, 0, stream>>>(ei, rowptr, fill, eid, pos,
                                               dstarr, scale_s, rezero);
  k_rev<<<(ED + 255) / 256, 256, 0, stream>>>(eid, pos, revslot);

  k_gemm1<<<NN / 8, 256, 0, stream>>>(x, W1, dinv, hw1);
  k_agg1<<<NN, 128, 0, stream>>>(hw1, dinv, rowptr, dstarr, b1, h1);
  k_gemm2<<<(NN + 255) / 256, 256, 0, stream>>>(h1, W2, dinv, hw2);
  k_agg2pre<<<NN / 32, 256, 0, stream>>>(hw2, dinv, rowptr, dstarr, b2, target,
                                         tmask, flag, phiu);
  k_phib<<<1, 64, 0, stream>>>(binary, phib);

  // m0 = 0 (after GCN, since hw1 aliases mA)
  hipMemsetAsync(mA, 0, (size_t)ED * NC * sizeof(float), stream);

  float* mcur = mA;
  float* mnxt = mB;
  for (int it = 0; it < BP_ITERS; it++) {
    k_bp<<<NN / NPB, 256, 0, stream>>>(mcur, mnxt, phiu, rowptr, revslot,
                                       scale_s, phib);
    float* tmp = mcur; mcur = mnxt; mnxt = tmp;
  }

  k_final<<<NN / NPB, 256, 0, stream>>>(mcur, phiu, rowptr, revslot, (float*)d_out);
}

// Round 9
// 2971.101 us; speedup vs baseline: 1.6218x; 1.1275x over previous
//
#include <hip/hip_runtime.h>
#include <hip/hip_bf16.h>

#define NN 20000
#define EU 320000
#define ED 640000
#define FIN 128
#define HD  128
#define NC  8
#define BP_ITERS 100
#define NPB 4      // nodes (waves) per block in BP kernels
#define GMAX 16    // register-cached edge groups (GMAX*8 = 128 edges max fast path)

#define LOG2E 1.4426950408889634f
#define LN2   0.6931471805599453f

// ---- workspace layout (4-byte units); hw1 aliases mA, h1 aliases mB ----
// Message storage is DST-CSR slot order: node v's INCOMING messages are the
// contiguous slots [rowptr[v], rowptr[v+1]).  k_bp reads coalesced, writes
// outgoing messages scattered via revslot (fire-and-forget stores).
enum {
  OFF_FLAG   = 0,                      // 4 ints
  OFF_DINV   = 4,                      // NN floats
  OFF_COUNT  = OFF_DINV  + NN,         // NN ints
  OFF_ROWPTR = OFF_COUNT + NN,         // NN+4 ints
  OFF_FILL   = OFF_ROWPTR+ NN + 4,     // NN ints
  OFF_EID    = OFF_FILL  + NN,         // ED ints  (slot -> directed edge id)
  OFF_POS    = OFF_EID   + ED,         // ED ints  (edge id -> slot)
  OFF_SRC    = OFF_POS   + ED,         // ED ints  (slot -> src node, for GCN gathers)
  OFF_REV    = OFF_SRC   + ED,         // ED ints  (slot -> slot of reverse edge)
  OFF_SCALE  = OFF_REV   + ED,         // ED floats (slot -> rezero scale of its ue)
  OFF_HW2    = OFF_SCALE + ED,         // NN*NC floats
  OFF_PHIU   = OFF_HW2   + NN*NC,      // NN*NC floats
  OFF_PHIB   = OFF_PHIU  + NN*NC,      // 64 floats
  OFF_MA     = OFF_PHIB  + 64,         // ED*NC floats (also hw1: NN*HD <= ED*NC)
  OFF_MB     = OFF_MA    + ED*NC,      // ED*NC floats (also h1)
  WS_WORDS   = OFF_MB    + ED*NC
};

__device__ __forceinline__ float fexp2(float x) {
#if __has_builtin(__builtin_amdgcn_exp2f)
  return __builtin_amdgcn_exp2f(x);
#else
  return exp2f(x);
#endif
}
__device__ __forceinline__ float flog2(float x) {
#if __has_builtin(__builtin_amdgcn_logf)
  return __builtin_amdgcn_logf(x);
#else
  return log2f(x);
#endif
}

// detect whether train_mask is byte(bool) or int32 layout.
__global__ void k_detect(const unsigned* tm, int* flag) {
  __shared__ int bad;
  if (threadIdx.x == 0) bad = 0;
  __syncthreads();
  for (int i = threadIdx.x; i < NN / 4; i += blockDim.x) {
    if (tm[i] > 1u) atomicOr(&bad, 1);
  }
  __syncthreads();
  if (threadIdx.x == 0) flag[0] = bad;  // 1 => byte layout
}

// count by DST: dst(e) = ei[rev(e)] by the concat construction
__global__ void k_count(const int* ei, int* cnt) {
  int e = blockIdx.x * blockDim.x + threadIdx.x;
  if (e < ED) {
    int er = (e < EU) ? e + EU : e - EU;
    atomicAdd(&cnt[ei[er]], 1);
  }
}

__global__ void k_scan(const int* cnt, int* rowptr) {
  __shared__ int s[1024];
  const int T = 1024, CH = (NN + T - 1) / T;
  int t = threadIdx.x;
  int base = t * CH;
  int loc = 0;
  for (int k = 0; k < CH; k++) {
    int idx = base + k;
    if (idx < NN) loc += cnt[idx];
  }
  s[t] = loc;
  __syncthreads();
  for (int off = 1; off < T; off <<= 1) {
    int v = (t >= off) ? s[t - off] : 0;
    __syncthreads();
    s[t] += v;
    __syncthreads();
  }
  int run = s[t] - loc;  // exclusive
  for (int k = 0; k < CH; k++) {
    int idx = base + k;
    if (idx < NN) { rowptr[idx] = run; run += cnt[idx]; }
  }
  if (t == T - 1) rowptr[NN] = run;
}

__global__ void k_dinv(const int* cnt, float* dinv) {
  int v = blockIdx.x * blockDim.x + threadIdx.x;
  if (v < NN) dinv[v] = rsqrtf((float)(cnt[v] + 1));
}

// fill dst-CSR: slot -> edge, edge -> slot, slot -> src node, slot -> scale
__global__ void k_fill(const int* ei, const int* rowptr, int* fill,
                       int* eid, int* pos, int* srcarr, float* scale_s,
                       const float* rezero) {
  int e = blockIdx.x * blockDim.x + threadIdx.x;
  if (e < ED) {
    int er = (e < EU) ? e + EU : e - EU;
    int dst = ei[er];
    int p = rowptr[dst] + atomicAdd(&fill[dst], 1);
    eid[p] = e;
    pos[e] = p;
    srcarr[p] = ei[e];
    scale_s[p] = rezero[(e < EU) ? e : e - EU];
  }
}

__global__ void k_rev(const int* eid, const int* pos, int* revslot) {
  int p = blockIdx.x * blockDim.x + threadIdx.x;
  if (p < ED) {
    int e = eid[p];
    int er = (e < EU) ? e + EU : e - EU;
    revslot[p] = pos[er];
  }
}

// hw1 = (x @ W1) * dinv[row].  No LDS staging: W1 (64KB) stays L2-hot;
// x reads are wave-uniform broadcasts.  32 rows/block -> 625 blocks exact.
__global__ __launch_bounds__(256) void k_gemm1(const float* __restrict__ x,
                                               const float* __restrict__ W1,
                                               const float* __restrict__ dinv,
                                               float* __restrict__ hw1) {
  int t = threadIdx.x;
  int c = t & 127, half = t >> 7;
  int r0 = blockIdx.x * 32 + half * 16;
  float acc[16];
#pragma unroll
  for (int r = 0; r < 16; r++) acc[r] = 0.f;
  for (int k = 0; k < FIN; k++) {
    float w = W1[k * HD + c];
#pragma unroll
    for (int r = 0; r < 16; r++)
      acc[r] += x[(r0 + r) * FIN + k] * w;
  }
#pragma unroll
  for (int r = 0; r < 16; r++)
    hw1[(r0 + r) * HD + c] = acc[r] * dinv[r0 + r];
}

// h1[v] = relu(dinv[v]*(sum_neighbors hw1[u] + hw1[v]) + b1)
__global__ __launch_bounds__(128) void k_agg1(const float* __restrict__ hw1,
                                              const float* __restrict__ dinv,
                                              const int* __restrict__ rowptr,
                                              const int* __restrict__ srcarr,
                                              const float* __restrict__ b1,
                                              float* __restrict__ h1) {
  int v = blockIdx.x;
  int f = threadIdx.x;
  int s0 = rowptr[v], s1 = rowptr[v + 1];
  float a0 = 0.f, a1 = 0.f, a2 = 0.f, a3 = 0.f;
  int s = s0;
  for (; s + 4 <= s1; s += 4) {
    int u0 = srcarr[s], u1 = srcarr[s + 1], u2 = srcarr[s + 2], u3 = srcarr[s + 3];
    a0 += hw1[u0 * HD + f];
    a1 += hw1[u1 * HD + f];
    a2 += hw1[u2 * HD + f];
    a3 += hw1[u3 * HD + f];
  }
  for (; s < s1; s++) a0 += hw1[srcarr[s] * HD + f];
  float acc = (a0 + a1) + (a2 + a3);
  float dv = dinv[v];
  float val = dv * (acc + hw1[v * HD + f]) + b1[f];
  h1[v * HD + f] = fmaxf(val, 0.f);
}

// hw2 = (h1 @ W2) * dinv[row]
__global__ __launch_bounds__(256) void k_gemm2(const float* __restrict__ h1,
                                               const float* __restrict__ W2,
                                               const float* __restrict__ dinv,
                                               float* __restrict__ hw2) {
  __shared__ float Ws[HD * NC];
  int t = threadIdx.x;
  for (int i = t; i < HD * NC; i += 256) Ws[i] = W2[i];
  __syncthreads();
  int v = blockIdx.x * 256 + t;
  if (v >= NN) return;
  float acc[NC];
#pragma unroll
  for (int c = 0; c < NC; c++) acc[c] = 0.f;
  const float4* hp = (const float4*)&h1[v * HD];
  for (int k4 = 0; k4 < HD / 4; k4++) {
    float4 h4 = hp[k4];
    float hv[4] = {h4.x, h4.y, h4.z, h4.w};
#pragma unroll
    for (int j = 0; j < 4; j++) {
      int k = k4 * 4 + j;
#pragma unroll
      for (int c = 0; c < NC; c++) acc[c] += hv[j] * Ws[k * NC + c];
    }
  }
  float dv = dinv[v];
#pragma unroll
  for (int c = 0; c < NC; c++) hw2[v * NC + c] = acc[c] * dv;
}

// unary -> phi_u (reference clamping), 32 nodes x 8 lanes per block
__global__ __launch_bounds__(256) void k_agg2pre(const float* __restrict__ hw2,
                                                 const float* __restrict__ dinv,
                                                 const int* __restrict__ rowptr,
                                                 const int* __restrict__ srcarr,
                                                 const float* __restrict__ b2,
                                                 const int* __restrict__ target,
                                                 const void* __restrict__ tmask,
                                                 const int* __restrict__ flag,
                                                 float* __restrict__ phi_u) {
  int t = threadIdx.x;
  int node = blockIdx.x * 32 + (t >> 3);
  int c = t & 7;
  if (node >= NN) return;
  int s0 = rowptr[node], s1 = rowptr[node + 1];
  float acc = 0.f;
  for (int s = s0; s < s1; s++) {
    int u = srcarr[s];
    acc += hw2[u * NC + c];
  }
  float dv = dinv[node];
  float unary = dv * (acc + hw2[node * NC + c]) + b2[c];
  float e = -unary;
  int tgt = target[node];
  float gt = __shfl(e, (t & ~7) | tgt, 64);  // GT energy gathered before masking
  bool mk;
  if (flag[0]) mk = ((const unsigned char*)tmask)[node] != 0;
  else         mk = ((const int*)tmask)[node] != 0;
  if (mk) e = (c == tgt) ? gt : 1e5f;
  float mn = e;
  mn = fminf(mn, __shfl_xor(mn, 1));
  mn = fminf(mn, __shfl_xor(mn, 2));
  mn = fminf(mn, __shfl_xor(mn, 4));
  e = fminf(e - mn, 20.0f);
  phi_u[node * NC + c] = -e;
}

// phi_b = B - max(B), B = (binary + binary^T)/2
__global__ void k_phib(const float* __restrict__ binary, float* __restrict__ phib) {
  int t = threadIdx.x;  // 64
  int i = t >> 3, j = t & 7;
  float B = 0.5f * (binary[i * NC + j] + binary[j * NC + i]);
  float mx = B;
#pragma unroll
  for (int d = 1; d < 64; d <<= 1) mx = fmaxf(mx, __shfl_xor(mx, d));
  phib[t] = B - mx;
}

// ---- fused BP iteration, dst-CSR layout: one wave per node ----
// Incoming messages of v are CONTIGUOUS slots [rowptr[v],rowptr[v+1]) ->
// coalesced reads.  Outgoing message for the edge pair of slot p is written
// scattered to revslot[p] (the slot in u's row).  Same math as before.
__global__ __launch_bounds__(256) void k_bp(const float* __restrict__ m,
                                            float* __restrict__ mout,
                                            const float* __restrict__ phiu,
                                            const int* __restrict__ rowptr,
                                            const int* __restrict__ revslot,
                                            const float* __restrict__ scale_s,
                                            const float* __restrict__ phib_g) {
  __shared__ float pb[64];
  int t = threadIdx.x;
  if (t < 64) pb[t] = phib_g[t];
  __syncthreads();
  int w = t >> 6, l = t & 63, le = l >> 3, c = l & 7;
  int v = blockIdx.x * NPB + w;
  int s0 = rowptr[v], deg = rowptr[v + 1] - s0;
  int ng = (deg + 7) >> 3;
  float pbr[8];
#pragma unroll
  for (int i = 0; i < 8; i++) pbr[i] = pb[i * 8 + c];

  // pass 1: coalesced read of own incoming row; accumulate node_in
  float mv[GMAX];
  float ni = 0.f;
#pragma unroll
  for (int g = 0; g < GMAX; g++) {
    mv[g] = 0.f;
    if (g < ng) {
      int q = g * 8 + le;
      if (q < deg) mv[g] = m[(s0 + q) * 8 + c];
      ni += mv[g];
    }
  }
  for (int g = GMAX; g < ng; g++) {  // cold overflow path (deg > 128)
    int q = g * 8 + le;
    if (q < deg) ni += m[(s0 + q) * 8 + c];
  }
  ni += __shfl_xor(ni, 8);
  ni += __shfl_xor(ni, 16);
  ni += __shfl_xor(ni, 32);
  float nph = phiu[v * 8 + c] + ni;   // uniform across le groups

  // pass 2: for incoming edge (u->v) at q, compute outgoing (v->u);
  // write scattered to the reverse slot (u's row).
#pragma unroll
  for (int g = 0; g < GMAX; g++) {
    if (g < ng) {
      int q = g * 8 + le;
      float hm = nph - mv[g];
      float mx = hm;
      mx = fmaxf(mx, __shfl_xor(mx, 1));
      mx = fmaxf(mx, __shfl_xor(mx, 2));
      mx = fmaxf(mx, __shfl_xor(mx, 4));
      float a = (hm - mx) * LOG2E;
      float sl = scale_s[s0 + (q < deg ? q : 0)] * LOG2E;
      float S = 0.f;
#pragma unroll
      for (int i = 0; i < 8; i++) {
        float ai = __shfl(a, (l & 56) | i, 64);
        S += fexp2(fmaf(sl, pbr[i], ai));
      }
      float out = fmaf(flog2(S), LN2, mx);
      float mm = out;
      mm = fmaxf(mm, __shfl_xor(mm, 1));
      mm = fmaxf(mm, __shfl_xor(mm, 2));
      mm = fmaxf(mm, __shfl_xor(mm, 4));
      float Z = fexp2((out - mm) * LOG2E);
      Z += __shfl_xor(Z, 1);
      Z += __shfl_xor(Z, 2);
      Z += __shfl_xor(Z, 4);
      float res = out - fmaf(flog2(Z), LN2, mm);
      if (q < deg) mout[revslot[s0 + q] * 8 + c] = res;
    }
  }
  for (int g = GMAX; g < ng; g++) {  // cold overflow path
    int q = g * 8 + le;
    float mvg = (q < deg) ? m[(s0 + q) * 8 + c] : 0.f;
    float hm = nph - mvg;
    float mx = hm;
    mx = fmaxf(mx, __shfl_xor(mx, 1));
    mx = fmaxf(mx, __shfl_xor(mx, 2));
    mx = fmaxf(mx, __shfl_xor(mx, 4));
    float a = (hm - mx) * LOG2E;
    float sl = scale_s[s0 + (q < deg ? q : 0)] * LOG2E;
    float S = 0.f;
#pragma unroll
    for (int i = 0; i < 8; i++) {
      float ai = __shfl(a, (l & 56) | i, 64);
      S += fexp2(fmaf(sl, pbr[i], ai));
    }
    float out = fmaf(flog2(S), LN2, mx);
    float mm = out;
    mm = fmaxf(mm, __shfl_xor(mm, 1));
    mm = fmaxf(mm, __shfl_xor(mm, 2));
    mm = fmaxf(mm, __shfl_xor(mm, 4));
    float Z = fexp2((out - mm) * LOG2E);
    Z += __shfl_xor(Z, 1);
    Z += __shfl_xor(Z, 2);
    Z += __shfl_xor(Z, 4);
    float res = out - fmaf(flog2(Z), LN2, mm);
    if (q < deg) mout[revslot[s0 + q] * 8 + c] = res;
  }
}

// beliefs = phi_u + sum of own contiguous incoming row; log_softmax -> out
__global__ __launch_bounds__(256) void k_final(const float* __restrict__ m,
                                               const float* __restrict__ phiu,
                                               const int* __restrict__ rowptr,
                                               float* __restrict__ out) {
  int t = threadIdx.x;
  int w = t >> 6, l = t & 63, le = l >> 3, c = l & 7;
  int v = blockIdx.x * NPB + w;
  int s0 = rowptr[v], deg = rowptr[v + 1] - s0;
  float ni = 0.f;
  for (int q = le; q < deg; q += 8) ni += m[(s0 + q) * 8 + c];
  ni += __shfl_xor(ni, 8);
  ni += __shfl_xor(ni, 16);
  ni += __shfl_xor(ni, 32);
  float bel = phiu[v * 8 + c] + ni;
  float mx = bel;
  mx = fmaxf(mx, __shfl_xor(mx, 1));
  mx = fmaxf(mx, __shfl_xor(mx, 2));
  mx = fmaxf(mx, __shfl_xor(mx, 4));
  float Z = fexp2((bel - mx) * LOG2E);
  Z += __shfl_xor(Z, 1);
  Z += __shfl_xor(Z, 2);
  Z += __shfl_xor(Z, 4);
  out[v * 8 + c] = bel - fmaf(flog2(Z), LN2, mx);
}

extern "C" void kernel_launch(void* const* d_in, const int* in_sizes, int n_in,
                              void* d_out, int out_size, void* d_ws, size_t ws_size,
                              hipStream_t stream) {
  const float* x      = (const float*)d_in[0];
  const int*   ei     = (const int*)d_in[1];
  const void*  tmask  = d_in[2];
  const int*   target = (const int*)d_in[3];
  const float* W1     = (const float*)d_in[4];
  const float* b1     = (const float*)d_in[5];
  const float* W2     = (const float*)d_in[6];
  const float* b2     = (const float*)d_in[7];
  const float* binary = (const float*)d_in[8];
  const float* rezero = (const float*)d_in[9];

  float* ws  = (float*)d_ws;
  int*   wsi = (int*)d_ws;

  int*   flag    = wsi + OFF_FLAG;
  float* dinv    = ws  + OFF_DINV;
  int*   cnt     = wsi + OFF_COUNT;
  int*   rowptr  = wsi + OFF_ROWPTR;
  int*   fill    = wsi + OFF_FILL;
  int*   eid     = wsi + OFF_EID;
  int*   pos     = wsi + OFF_POS;
  int*   srcarr  = wsi + OFF_SRC;
  int*   revslot = wsi + OFF_REV;
  float* scale_s = ws  + OFF_SCALE;
  float* hw2     = ws  + OFF_HW2;
  float* phiu    = ws  + OFF_PHIU;
  float* phib    = ws  + OFF_PHIB;
  float* mA      = ws  + OFF_MA;
  float* mB      = ws  + OFF_MB;
  float* hw1     = mA;  // aliased: GCN scratch reuses message buffers
  float* h1      = mB;

  hipMemsetAsync(cnt, 0, NN * sizeof(int), stream);
  hipMemsetAsync(fill, 0, NN * sizeof(int), stream);

  k_detect<<<1, 1024, 0, stream>>>((const unsigned*)tmask, flag);
  k_count<<<(ED + 255) / 256, 256, 0, stream>>>(ei, cnt);
  k_scan<<<1, 1024, 0, stream>>>(cnt, rowptr);
  k_dinv<<<(NN + 255) / 256, 256, 0, stream>>>(cnt, dinv);
  k_fill<<<(ED + 255) / 256, 256, 0, stream>>>(ei, rowptr, fill, eid, pos,
                                               srcarr, scale_s, rezero);
  k_rev<<<(ED + 255) / 256, 256, 0, stream>>>(eid, pos, revslot);

  k_gemm1<<<NN / 32, 256, 0, stream>>>(x, W1, dinv, hw1);
  k_agg1<<<NN, 128, 0, stream>>>(hw1, dinv, rowptr, srcarr, b1, h1);
  k_gemm2<<<(NN + 255) / 256, 256, 0, stream>>>(h1, W2, dinv, hw2);
  k_agg2pre<<<NN / 32, 256, 0, stream>>>(hw2, dinv, rowptr, srcarr, b2, target,
                                         tmask, flag, phiu);
  k_phib<<<1, 64, 0, stream>>>(binary, phib);

  // m0 = 0 (after GCN, since hw1 aliases mA)
  hipMemsetAsync(mA, 0, (size_t)ED * NC * sizeof(float), stream);

  float* mcur = mA;
  float* mnxt = mB;
  for (int it = 0; it < BP_ITERS; it++) {
    k_bp<<<NN / NPB, 256, 0, stream>>>(mcur, mnxt, phiu, rowptr, revslot,
                                       scale_s, phib);
    float* tmp = mcur; mcur = mnxt; mnxt = tmp;
  }

  k_final<<<NN / NPB, 256, 0, stream>>>(mcur, phiu, rowptr, (float*)d_out);
}

// Round 11
// 2560.574 us; speedup vs baseline: 1.8818x; 1.1603x over previous
//
#include <hip/hip_runtime.h>
#include <hip/hip_bf16.h>

#define NN 20000
#define EU 320000
#define ED 640000
#define FIN 128
#define HD  128
#define NC  8
#define BP_ITERS 100
#define NPB 4      // nodes (waves) per block in node-sum kernels

#define LOG2E 1.4426950408889634f
#define LN2   0.6931471805599453f

// ---- workspace layout (4-byte units); hw1 aliases mA, h1 aliases mB ----
// Messages in DST-CSR slot order: node v's INCOMING messages are contiguous
// slots [rowptr[v], rowptr[v+1]).  k_node sums rows coalesced -> nphi.
// k_edge is lane-per-slot: for slot p (edge u->v) it computes the REVERSE
// message (v->u) = LSE(nphi[v] - m[p] + scale*phib) and writes it scattered
// to revslot[p].  eid[] is repurposed as dstof[] (slot -> owner v) by k_rev.
enum {
  OFF_FLAG   = 0,                      // 4 ints
  OFF_DINV   = 4,                      // NN floats
  OFF_COUNT  = OFF_DINV  + NN,         // NN ints
  OFF_ROWPTR = OFF_COUNT + NN,         // NN+4 ints
  OFF_FILL   = OFF_ROWPTR+ NN + 4,     // NN ints
  OFF_EID    = OFF_FILL  + NN,         // ED ints  (slot -> edge id; later slot -> owner node)
  OFF_POS    = OFF_EID   + ED,         // ED ints  (edge id -> slot)
  OFF_SRC    = OFF_POS   + ED,         // ED ints  (slot -> src node, for GCN gathers)
  OFF_REV    = OFF_SRC   + ED,         // ED ints  (slot -> slot of reverse edge)
  OFF_SCALE  = OFF_REV   + ED,         // ED floats (slot -> rezero scale of its undirected edge)
  OFF_HW2    = OFF_SCALE + ED,         // NN*NC floats
  OFF_PHIU   = OFF_HW2   + NN*NC,      // NN*NC floats
  OFF_PHIB   = OFF_PHIU  + NN*NC,      // 64 floats
  OFF_NPHI   = OFF_PHIB  + 64,         // NN*NC floats
  OFF_MA     = OFF_NPHI  + NN*NC,      // ED*NC floats (also hw1: NN*HD <= ED*NC)
  OFF_MB     = OFF_MA    + ED*NC,      // ED*NC floats (also h1)
  WS_WORDS   = OFF_MB    + ED*NC
};

__device__ __forceinline__ float fexp2(float x) {
#if __has_builtin(__builtin_amdgcn_exp2f)
  return __builtin_amdgcn_exp2f(x);
#else
  return exp2f(x);
#endif
}
__device__ __forceinline__ float flog2(float x) {
#if __has_builtin(__builtin_amdgcn_logf)
  return __builtin_amdgcn_logf(x);
#else
  return log2f(x);
#endif
}

// detect whether train_mask is byte(bool) or int32 layout.
__global__ void k_detect(const unsigned* tm, int* flag) {
  __shared__ int bad;
  if (threadIdx.x == 0) bad = 0;
  __syncthreads();
  for (int i = threadIdx.x; i < NN / 4; i += blockDim.x) {
    if (tm[i] > 1u) atomicOr(&bad, 1);
  }
  __syncthreads();
  if (threadIdx.x == 0) flag[0] = bad;  // 1 => byte layout
}

// count by DST: dst(e) = ei[rev(e)] by the concat construction
__global__ void k_count(const int* ei, int* cnt) {
  int e = blockIdx.x * blockDim.x + threadIdx.x;
  if (e < ED) {
    int er = (e < EU) ? e + EU : e - EU;
    atomicAdd(&cnt[ei[er]], 1);
  }
}

__global__ void k_scan(const int* cnt, int* rowptr) {
  __shared__ int s[1024];
  const int T = 1024, CH = (NN + T - 1) / T;
  int t = threadIdx.x;
  int base = t * CH;
  int loc = 0;
  for (int k = 0; k < CH; k++) {
    int idx = base + k;
    if (idx < NN) loc += cnt[idx];
  }
  s[t] = loc;
  __syncthreads();
  for (int off = 1; off < T; off <<= 1) {
    int v = (t >= off) ? s[t - off] : 0;
    __syncthreads();
    s[t] += v;
    __syncthreads();
  }
  int run = s[t] - loc;  // exclusive
  for (int k = 0; k < CH; k++) {
    int idx = base + k;
    if (idx < NN) { rowptr[idx] = run; run += cnt[idx]; }
  }
  if (t == T - 1) rowptr[NN] = run;
}

__global__ void k_dinv(const int* cnt, float* dinv) {
  int v = blockIdx.x * blockDim.x + threadIdx.x;
  if (v < NN) dinv[v] = rsqrtf((float)(cnt[v] + 1));
}

// fill dst-CSR: slot -> edge, edge -> slot, slot -> src node, slot -> scale
__global__ void k_fill(const int* ei, const int* rowptr, int* fill,
                       int* eid, int* pos, int* srcarr, float* scale_s,
                       const float* rezero) {
  int e = blockIdx.x * blockDim.x + threadIdx.x;
  if (e < ED) {
    int er = (e < EU) ? e + EU : e - EU;
    int dst = ei[er];
    int p = rowptr[dst] + atomicAdd(&fill[dst], 1);
    eid[p] = e;
    pos[e] = p;
    srcarr[p] = ei[e];
    scale_s[p] = rezero[(e < EU) ? e : e - EU];
  }
}

// revslot[p] = slot of reverse edge; then repurpose eid[p] as owner node (dst)
__global__ void k_rev(int* eid, const int* pos, int* revslot, const int* ei) {
  int p = blockIdx.x * blockDim.x + threadIdx.x;
  if (p < ED) {
    int e = eid[p];
    int er = (e < EU) ? e + EU : e - EU;
    revslot[p] = pos[er];
    eid[p] = ei[er];   // dstof: owner node of slot p
  }
}

// hw1 = (x @ W1) * dinv[row].  16 rows/block -> 1250 blocks (4.9/CU).
// x row-chunk reads are wave-uniform (s_load-able); W1 column reads vectorized.
__global__ __launch_bounds__(256) void k_gemm1(const float* __restrict__ x,
                                               const float* __restrict__ W1,
                                               const float* __restrict__ dinv,
                                               float* __restrict__ hw1) {
  int t = threadIdx.x;
  int c = t & 127, half = t >> 7;
  int r0 = blockIdx.x * 16 + half * 8;
  float acc[8];
#pragma unroll
  for (int r = 0; r < 8; r++) acc[r] = 0.f;
  for (int k = 0; k < FIN; k += 4) {
    float w0 = W1[k * HD + c];
    float w1 = W1[(k + 1) * HD + c];
    float w2 = W1[(k + 2) * HD + c];
    float w3 = W1[(k + 3) * HD + c];
#pragma unroll
    for (int r = 0; r < 8; r++) {
      float4 xr = *(const float4*)&x[(r0 + r) * FIN + k];  // wave-uniform
      acc[r] += xr.x * w0 + xr.y * w1 + xr.z * w2 + xr.w * w3;
    }
  }
#pragma unroll
  for (int r = 0; r < 8; r++)
    hw1[(r0 + r) * HD + c] = acc[r] * dinv[r0 + r];
}

// h1[v] = relu(dinv[v]*(sum_neighbors hw1[u] + hw1[v]) + b1)
__global__ __launch_bounds__(128) void k_agg1(const float* __restrict__ hw1,
                                              const float* __restrict__ dinv,
                                              const int* __restrict__ rowptr,
                                              const int* __restrict__ srcarr,
                                              const float* __restrict__ b1,
                                              float* __restrict__ h1) {
  int v = blockIdx.x;
  int f = threadIdx.x;
  int s0 = rowptr[v], s1 = rowptr[v + 1];
  float a0 = 0.f, a1 = 0.f, a2 = 0.f, a3 = 0.f;
  int s = s0;
  for (; s + 4 <= s1; s += 4) {
    int u0 = srcarr[s], u1 = srcarr[s + 1], u2 = srcarr[s + 2], u3 = srcarr[s + 3];
    a0 += hw1[u0 * HD + f];
    a1 += hw1[u1 * HD + f];
    a2 += hw1[u2 * HD + f];
    a3 += hw1[u3 * HD + f];
  }
  for (; s < s1; s++) a0 += hw1[srcarr[s] * HD + f];
  float acc = (a0 + a1) + (a2 + a3);
  float dv = dinv[v];
  float val = dv * (acc + hw1[v * HD + f]) + b1[f];
  h1[v * HD + f] = fmaxf(val, 0.f);
}

// hw2 = (h1 @ W2) * dinv[row]
__global__ __launch_bounds__(256) void k_gemm2(const float* __restrict__ h1,
                                               const float* __restrict__ W2,
                                               const float* __restrict__ dinv,
                                               float* __restrict__ hw2) {
  __shared__ float Ws[HD * NC];
  int t = threadIdx.x;
  for (int i = t; i < HD * NC; i += 256) Ws[i] = W2[i];
  __syncthreads();
  int v = blockIdx.x * 256 + t;
  if (v >= NN) return;
  float acc[NC];
#pragma unroll
  for (int c = 0; c < NC; c++) acc[c] = 0.f;
  const float4* hp = (const float4*)&h1[v * HD];
  for (int k4 = 0; k4 < HD / 4; k4++) {
    float4 h4 = hp[k4];
    float hv[4] = {h4.x, h4.y, h4.z, h4.w};
#pragma unroll
    for (int j = 0; j < 4; j++) {
      int k = k4 * 4 + j;
#pragma unroll
      for (int c = 0; c < NC; c++) acc[c] += hv[j] * Ws[k * NC + c];
    }
  }
  float dv = dinv[v];
#pragma unroll
  for (int c = 0; c < NC; c++) hw2[v * NC + c] = acc[c] * dv;
}

// unary -> phi_u (reference clamping), 32 nodes x 8 lanes per block
__global__ __launch_bounds__(256) void k_agg2pre(const float* __restrict__ hw2,
                                                 const float* __restrict__ dinv,
                                                 const int* __restrict__ rowptr,
                                                 const int* __restrict__ srcarr,
                                                 const float* __restrict__ b2,
                                                 const int* __restrict__ target,
                                                 const void* __restrict__ tmask,
                                                 const int* __restrict__ flag,
                                                 float* __restrict__ phi_u) {
  int t = threadIdx.x;
  int node = blockIdx.x * 32 + (t >> 3);
  int c = t & 7;
  if (node >= NN) return;
  int s0 = rowptr[node], s1 = rowptr[node + 1];
  float acc = 0.f;
  for (int s = s0; s < s1; s++) {
    int u = srcarr[s];
    acc += hw2[u * NC + c];
  }
  float dv = dinv[node];
  float unary = dv * (acc + hw2[node * NC + c]) + b2[c];
  float e = -unary;
  int tgt = target[node];
  float gt = __shfl(e, (t & ~7) | tgt, 64);  // GT energy gathered before masking
  bool mk;
  if (flag[0]) mk = ((const unsigned char*)tmask)[node] != 0;
  else         mk = ((const int*)tmask)[node] != 0;
  if (mk) e = (c == tgt) ? gt : 1e5f;
  float mn = e;
  mn = fminf(mn, __shfl_xor(mn, 1));
  mn = fminf(mn, __shfl_xor(mn, 2));
  mn = fminf(mn, __shfl_xor(mn, 4));
  e = fminf(e - mn, 20.0f);
  phi_u[node * NC + c] = -e;
}

// phi_b = B - max(B), B = (binary + binary^T)/2
__global__ void k_phib(const float* __restrict__ binary, float* __restrict__ phib) {
  int t = threadIdx.x;  // 64
  int i = t >> 3, j = t & 7;
  float B = 0.5f * (binary[i * NC + j] + binary[j * NC + i]);
  float mx = B;
#pragma unroll
  for (int d = 1; d < 64; d <<= 1) mx = fmaxf(mx, __shfl_xor(mx, d));
  phib[t] = B - mx;
}

// nphi[v] = phi_u[v] + sum of v's contiguous incoming row (coalesced)
__global__ __launch_bounds__(256) void k_node(const float* __restrict__ m,
                                              const float* __restrict__ phiu,
                                              const int* __restrict__ rowptr,
                                              float* __restrict__ nphi) {
  int t = threadIdx.x;
  int w = t >> 6, l = t & 63, le = l >> 3, c = l & 7;
  int v = blockIdx.x * NPB + w;
  int s0 = rowptr[v], deg = rowptr[v + 1] - s0;
  float ni = 0.f;
  for (int q = le; q < deg; q += 8) ni += m[(s0 + q) * 8 + c];
  ni += __shfl_xor(ni, 8);
  ni += __shfl_xor(ni, 16);
  ni += __shfl_xor(ni, 32);
  if (le == 0) nphi[v * 8 + c] = phiu[v * 8 + c] + ni;
}

// lane-per-slot BP update: slot p holds m for edge (u->v); compute the
// reverse message (v->u) fully in registers, write to revslot[p].
__global__ __launch_bounds__(256) void k_edge(const float* __restrict__ m,
                                              float* __restrict__ mout,
                                              const float* __restrict__ nphi,
                                              const int* __restrict__ dstof,
                                              const int* __restrict__ revslot,
                                              const float* __restrict__ scale_s,
                                              const float* __restrict__ phib_g) {
  int p = blockIdx.x * 256 + threadIdx.x;   // ED is a multiple of 256
  int v = dstof[p];
  float4 m0 = *(const float4*)&m[p * 8];
  float4 m1 = *(const float4*)&m[p * 8 + 4];
  float4 n0 = *(const float4*)&nphi[v * 8];
  float4 n1 = *(const float4*)&nphi[v * 8 + 4];
  float hm[8] = {n0.x - m0.x, n0.y - m0.y, n0.z - m0.z, n0.w - m0.w,
                 n1.x - m1.x, n1.y - m1.y, n1.z - m1.z, n1.w - m1.w};
  float mx = hm[0];
#pragma unroll
  for (int i = 1; i < 8; i++) mx = fmaxf(mx, hm[i]);
  float a[8];
#pragma unroll
  for (int i = 0; i < 8; i++) a[i] = (hm[i] - mx) * LOG2E;
  float sl = scale_s[p] * LOG2E;
  float out[8];
#pragma unroll
  for (int j = 0; j < 8; j++) {
    float S = 0.f;
#pragma unroll
    for (int i = 0; i < 8; i++)
      S += fexp2(fmaf(sl, phib_g[i * 8 + j], a[i]));  // phib: wave-uniform s_loads
    out[j] = fmaf(flog2(S), LN2, mx);
  }
  // renormalize (exact LSE over labels)
  float mm = out[0];
#pragma unroll
  for (int j = 1; j < 8; j++) mm = fmaxf(mm, out[j]);
  float Z = 0.f;
#pragma unroll
  for (int j = 0; j < 8; j++) Z += fexp2((out[j] - mm) * LOG2E);
  float lse = fmaf(flog2(Z), LN2, mm);
  int rp = revslot[p];
  float4 o0 = make_float4(out[0] - lse, out[1] - lse, out[2] - lse, out[3] - lse);
  float4 o1 = make_float4(out[4] - lse, out[5] - lse, out[6] - lse, out[7] - lse);
  *(float4*)&mout[rp * 8] = o0;
  *(float4*)&mout[rp * 8 + 4] = o1;
}

// beliefs = phi_u + sum of own contiguous incoming row; log_softmax -> out
__global__ __launch_bounds__(256) void k_final(const float* __restrict__ m,
                                               const float* __restrict__ phiu,
                                               const int* __restrict__ rowptr,
                                               float* __restrict__ out) {
  int t = threadIdx.x;
  int w = t >> 6, l = t & 63, le = l >> 3, c = l & 7;
  int v = blockIdx.x * NPB + w;
  int s0 = rowptr[v], deg = rowptr[v + 1] - s0;
  float ni = 0.f;
  for (int q = le; q < deg; q += 8) ni += m[(s0 + q) * 8 + c];
  ni += __shfl_xor(ni, 8);
  ni += __shfl_xor(ni, 16);
  ni += __shfl_xor(ni, 32);
  float bel = phiu[v * 8 + c] + ni;
  float mx = bel;
  mx = fmaxf(mx, __shfl_xor(mx, 1));
  mx = fmaxf(mx, __shfl_xor(mx, 2));
  mx = fmaxf(mx, __shfl_xor(mx, 4));
  float Z = fexp2((bel - mx) * LOG2E);
  Z += __shfl_xor(Z, 1);
  Z += __shfl_xor(Z, 2);
  Z += __shfl_xor(Z, 4);
  out[v * 8 + c] = bel - fmaf(flog2(Z), LN2, mx);
}

extern "C" void kernel_launch(void* const* d_in, const int* in_sizes, int n_in,
                              void* d_out, int out_size, void* d_ws, size_t ws_size,
                              hipStream_t stream) {
  const float* x      = (const float*)d_in[0];
  const int*   ei     = (const int*)d_in[1];
  const void*  tmask  = d_in[2];
  const int*   target = (const int*)d_in[3];
  const float* W1     = (const float*)d_in[4];
  const float* b1     = (const float*)d_in[5];
  const float* W2     = (const float*)d_in[6];
  const float* b2     = (const float*)d_in[7];
  const float* binary = (const float*)d_in[8];
  const float* rezero = (const float*)d_in[9];

  float* ws  = (float*)d_ws;
  int*   wsi = (int*)d_ws;

  int*   flag    = wsi + OFF_FLAG;
  float* dinv    = ws  + OFF_DINV;
  int*   cnt     = wsi + OFF_COUNT;
  int*   rowptr  = wsi + OFF_ROWPTR;
  int*   fill    = wsi + OFF_FILL;
  int*   eid     = wsi + OFF_EID;   // becomes dstof after k_rev
  int*   pos     = wsi + OFF_POS;
  int*   srcarr  = wsi + OFF_SRC;
  int*   revslot = wsi + OFF_REV;
  float* scale_s = ws  + OFF_SCALE;
  float* hw2     = ws  + OFF_HW2;
  float* phiu    = ws  + OFF_PHIU;
  float* phib    = ws  + OFF_PHIB;
  float* nphi    = ws  + OFF_NPHI;
  float* mA      = ws  + OFF_MA;
  float* mB      = ws  + OFF_MB;
  float* hw1     = mA;  // aliased: GCN scratch reuses message buffers
  float* h1      = mB;

  hipMemsetAsync(cnt, 0, NN * sizeof(int), stream);
  hipMemsetAsync(fill, 0, NN * sizeof(int), stream);

  k_detect<<<1, 1024, 0, stream>>>((const unsigned*)tmask, flag);
  k_count<<<(ED + 255) / 256, 256, 0, stream>>>(ei, cnt);
  k_scan<<<1, 1024, 0, stream>>>(cnt, rowptr);
  k_dinv<<<(NN + 255) / 256, 256, 0, stream>>>(cnt, dinv);
  k_fill<<<(ED + 255) / 256, 256, 0, stream>>>(ei, rowptr, fill, eid, pos,
                                               srcarr, scale_s, rezero);
  k_rev<<<(ED + 255) / 256, 256, 0, stream>>>(eid, pos, revslot, ei);

  k_gemm1<<<NN / 16, 256, 0, stream>>>(x, W1, dinv, hw1);
  k_agg1<<<NN, 128, 0, stream>>>(hw1, dinv, rowptr, srcarr, b1, h1);
  k_gemm2<<<(NN + 255) / 256, 256, 0, stream>>>(h1, W2, dinv, hw2);
  k_agg2pre<<<NN / 32, 256, 0, stream>>>(hw2, dinv, rowptr, srcarr, b2, target,
                                         tmask, flag, phiu);
  k_phib<<<1, 64, 0, stream>>>(binary, phib);

  // m0 = 0 (after GCN, since hw1 aliases mA)
  hipMemsetAsync(mA, 0, (size_t)ED * NC * sizeof(float), stream);

  float* mcur = mA;
  float* mnxt = mB;
  for (int it = 0; it < BP_ITERS; it++) {
    k_node<<<NN / NPB, 256, 0, stream>>>(mcur, phiu, rowptr, nphi);
    k_edge<<<ED / 256, 256, 0, stream>>>(mcur, mnxt, nphi, eid, revslot,
                                         scale_s, phib);
    float* tmp = mcur; mcur = mnxt; mnxt = tmp;
  }

  k_final<<<NN / NPB, 256, 0, stream>>>(mcur, phiu, rowptr, (float*)d_out);
}